// Round 3
// baseline (212.455 us; speedup 1.0000x reference)
//
#include <hip/hip_runtime.h>

// Problem constants
#define BATCH 1024
#define NIN   512
#define NOUT  512
#define NB    11
#define KSPLINE (NIN * NB)        // 5632
#define KDIM    (KSPLINE + NIN)   // 6144
#define SPLITS  16
#define BK      64
#define KCHUNK  (KDIM / SPLITS)   // 384
#define NTILES  32                // (1024/128) * (512/128)
#define TILE_ELEMS (128 * 128)    // 16384

typedef short bf16x8 __attribute__((ext_vector_type(8)));
typedef float f32x4  __attribute__((ext_vector_type(4)));
typedef unsigned short ushort8 __attribute__((ext_vector_type(8)));

__device__ __forceinline__ unsigned short f2bf(float f) {
  unsigned u = __float_as_uint(f);
  u += 0x7fff + ((u >> 16) & 1);   // RNE to bf16
  return (unsigned short)(u >> 16);
}

// K1 fused prep:
//  blocks [0,2048):      basis+silu -> A [1024][6144] bf16, LDS-staged 16B stores
//  blocks [2048,3584):   Bt[o][kk], 8 outputs/thread, one 16B store
//  block 0 also zeroes the split-K tile counters.
__global__ __launch_bounds__(256) void k_prep(const float* __restrict__ x,
                                              const float* __restrict__ c,
                                              const float* __restrict__ w,
                                              unsigned short* __restrict__ A,
                                              unsigned short* __restrict__ Bt,
                                              int* __restrict__ cnt) {
  int blk = blockIdx.x;
  int tid = threadIdx.x;
  if (blk < 2048) {
    if (blk == 0 && tid < NTILES) cnt[tid] = 0;
    __shared__ unsigned short sb[256 * NB + 256];  // 6 KB: basis rows + silu
    int b  = blk >> 1;
    int i0 = (blk & 1) * 256;
    int i  = i0 + tid;
    float xv = x[b * NIN + i];
    float B[14];
#pragma unroll
    for (int j = 0; j < 14; ++j) {
      float t0 = -5.25f + 0.75f * (float)j;
      float t1 = t0 + 0.75f;
      B[j] = (xv >= t0 && xv < t1) ? 1.0f : 0.0f;
    }
#pragma unroll
    for (int d = 1; d <= 3; ++d) {
      float inv = 1.0f / (0.75f * (float)d);
#pragma unroll
      for (int j = 0; j <= 13 - d; ++j) {
        float tj   = -5.25f + 0.75f * (float)j;
        float tjd1 = tj + 0.75f * (float)(d + 1);
        B[j] = (xv - tj) * inv * B[j] + (tjd1 - xv) * inv * B[j + 1];
      }
    }
#pragma unroll
    for (int j = 0; j < NB; ++j) sb[tid * NB + j] = f2bf(B[j]);
    float sig = 1.0f / (1.0f + __expf(-xv));
    sb[256 * NB + tid] = f2bf(xv * sig);
    __syncthreads();
    // cooperative 16B copy: 352 chunks of basis + 32 chunks of silu = 384
    char* Ab = (char*)A;
    const f32x4* src = (const f32x4*)sb;
    size_t base = (size_t)b * KDIM * 2;
#pragma unroll
    for (int t = tid; t < 384; t += 256) {
      size_t dst;
      if (t < 352) dst = base + (size_t)i0 * NB * 2 + (size_t)t * 16;
      else         dst = base + (size_t)KSPLINE * 2 + (size_t)i0 * 2 + (size_t)(t - 352) * 16;
      *(f32x4*)(Ab + dst) = src[t];
    }
  } else {
    int bc  = blk - 2048;
    int o   = bc & 511;
    int seg = bc >> 9;                 // 0..2
    int kk0 = seg * 2048 + tid * 8;    // multiple of 8
    ushort8 r;
#pragma unroll
    for (int u = 0; u < 8; ++u) {
      int kk = kk0 + u;
      float v;
      if (kk < KSPLINE) {
        int i = kk / NB;
        int k = kk - i * NB;
        v = c[(size_t)i * KSPLINE + o * NB + k] * w[i * NOUT + o];
      } else {
        v = w[(kk - KSPLINE) * NOUT + o];
      }
      r[u] = f2bf(v);
    }
    *(ushort8*)&Bt[(size_t)o * KDIM + kk0] = r;
  }
}

// K2: split-K GEMM + fused last-block reduction.
// 128x128 block tile, 4 waves 2x2, wave = 64x64 via 4x4 of 16x16x32 bf16 MFMA.
// XOR-swizzled LDS (conflict-free ds_read_b128). Partials per-tile contiguous.
__global__ __launch_bounds__(256) void k_gemm(const unsigned short* __restrict__ A,
                                              const unsigned short* __restrict__ Bt,
                                              float* __restrict__ part,
                                              int* __restrict__ cnt,
                                              float* __restrict__ out,
                                              int splits, int kchunk) {
  __shared__ unsigned short As[128 * BK];  // 16 KB
  __shared__ unsigned short Bs[128 * BK];  // 16 KB
  __shared__ int isLast;
  const int tid  = threadIdx.x;
  const int lane = tid & 63, wave = tid >> 6;
  const int wr = wave >> 1, wc = wave & 1;
  const int mbase = blockIdx.x * 128, nbase = blockIdx.y * 128;
  const int split = blockIdx.z;
  const int k0 = split * kchunk;
  const int tileid = blockIdx.y * 8 + blockIdx.x;

  f32x4 acc[4][4] = {};

  const int mrow = lane & 15;
  const int kq   = (lane >> 4) * 8;   // k-offset of this quarter-wave's frag
  const int swz  = mrow & 7;          // row-dependent XOR for LDS de-swizzle

  for (int kk = k0; kk < k0 + kchunk; kk += BK) {
    // stage A,Bt tiles: 128 rows x 64 bf16 = 128 B/row = 8 x 16B chunks.
    // LDS dest forced to base+lane*16 -> swizzle the GLOBAL column group.
#pragma unroll
    for (int it = 0; it < 4; ++it) {
      int ch  = it * 256 + tid;
      int row = ch >> 3;
      int cgl = ch & 7;
      int col = (cgl ^ (row & 7)) * 8;
      const unsigned short* ga = A  + (size_t)(mbase + row) * KDIM + kk + col;
      const unsigned short* gb = Bt + (size_t)(nbase + row) * KDIM + kk + col;
      unsigned short* la = As + (it * 256 + wave * 64) * 8;
      unsigned short* lb = Bs + (it * 256 + wave * 64) * 8;
      __builtin_amdgcn_global_load_lds((__attribute__((address_space(1))) const void*)ga,
                                       (__attribute__((address_space(3))) void*)la, 16, 0, 0);
      __builtin_amdgcn_global_load_lds((__attribute__((address_space(1))) const void*)gb,
                                       (__attribute__((address_space(3))) void*)lb, 16, 0, 0);
    }
    __syncthreads();

#pragma unroll
    for (int ks = 0; ks < BK; ks += 32) {
      bf16x8 af[4], bfr[4];
#pragma unroll
      for (int mt = 0; mt < 4; ++mt) {
        int row = wr * 64 + mt * 16 + mrow;
        int cg  = ((ks + kq) >> 3) ^ swz;
        af[mt] = *(const bf16x8*)&As[row * BK + cg * 8];
      }
#pragma unroll
      for (int nt = 0; nt < 4; ++nt) {
        int row = wc * 64 + nt * 16 + mrow;
        int cg  = ((ks + kq) >> 3) ^ swz;
        bfr[nt] = *(const bf16x8*)&Bs[row * BK + cg * 8];
      }
#pragma unroll
      for (int mt = 0; mt < 4; ++mt)
#pragma unroll
        for (int nt = 0; nt < 4; ++nt)
          acc[mt][nt] = __builtin_amdgcn_mfma_f32_16x16x32_bf16(af[mt], bfr[nt], acc[mt][nt], 0, 0, 0);
    }
    __syncthreads();
  }

  // epilogue: C/D layout col = lane&15, row = (lane>>4)*4 + reg
  const int rq = (lane >> 4) * 4;
  if (splits == 1) {
#pragma unroll
    for (int mt = 0; mt < 4; ++mt)
#pragma unroll
      for (int nt = 0; nt < 4; ++nt) {
        int colc = wc * 64 + nt * 16 + mrow;
#pragma unroll
        for (int r = 0; r < 4; ++r) {
          int l = wr * 64 + mt * 16 + rq + r;
          out[(size_t)(mbase + l) * NOUT + nbase + colc] = acc[mt][nt][r];
        }
      }
    return;
  }

  float* ptile = part + (size_t)tileid * SPLITS * TILE_ELEMS;
  float* mine  = ptile + (size_t)split * TILE_ELEMS;
#pragma unroll
  for (int mt = 0; mt < 4; ++mt)
#pragma unroll
    for (int nt = 0; nt < 4; ++nt) {
      int colc = wc * 64 + nt * 16 + mrow;
#pragma unroll
      for (int r = 0; r < 4; ++r) {
        int l = wr * 64 + mt * 16 + rq + r;
        mine[l * 128 + colc] = acc[mt][nt][r];
      }
    }

  __threadfence();  // release partials (device scope)
  if (tid == 0) {
    int old = __hip_atomic_fetch_add(&cnt[tileid], 1, __ATOMIC_ACQ_REL,
                                     __HIP_MEMORY_SCOPE_AGENT);
    isLast = (old == SPLITS - 1);
  }
  __syncthreads();
  if (!isLast) return;
  __threadfence();  // acquire others' partials

  const f32x4* pv = (const f32x4*)ptile;
#pragma unroll 1
  for (int cch = tid; cch < TILE_ELEMS / 4; cch += 256) {
    f32x4 s = pv[cch];
#pragma unroll
    for (int sp = 1; sp < SPLITS; ++sp)
      s += pv[(size_t)sp * (TILE_ELEMS / 4) + cch];
    int e = cch * 4;
    int row = e >> 7, col = e & 127;
    *(f32x4*)&out[(size_t)(mbase + row) * NOUT + nbase + col] = s;
  }
}

extern "C" void kernel_launch(void* const* d_in, const int* in_sizes, int n_in,
                              void* d_out, int out_size, void* d_ws, size_t ws_size,
                              hipStream_t stream) {
  const float* x = (const float*)d_in[0];
  const float* c = (const float*)d_in[1];
  const float* w = (const float*)d_in[2];
  float* out = (float*)d_out;

  unsigned short* A  = (unsigned short*)d_ws;
  unsigned short* Bt = A + (size_t)BATCH * KDIM;
  size_t off_part = ((size_t)BATCH + NOUT) * KDIM * 2;                 // 18,874,368
  float* part = (float*)((char*)d_ws + off_part);
  size_t off_cnt = off_part + (size_t)NTILES * SPLITS * TILE_ELEMS * 4; // +33,554,432
  int* cnt = (int*)((char*)d_ws + off_cnt);
  size_t need = off_cnt + NTILES * 4;

  k_prep<<<dim3(2048 + 512 * 3), 256, 0, stream>>>(x, c, w, A, Bt, cnt);
  if (ws_size >= need) {
    k_gemm<<<dim3(8, 4, SPLITS), 256, 0, stream>>>(A, Bt, part, cnt, out, SPLITS, KCHUNK);
  } else {
    // fallback: single-pass GEMM straight to out (slower, correct)
    k_gemm<<<dim3(8, 4, 1), 256, 0, stream>>>(A, Bt, part, cnt, out, 1, KDIM);
  }
}

// Round 4
// 117.460 us; speedup vs baseline: 1.8087x; 1.8087x over previous
//
#include <hip/hip_runtime.h>

// Problem constants
#define BATCH 1024
#define NIN   512
#define NOUT  512
#define NB    11
#define KSPLINE (NIN * NB)        // 5632
#define KDIM    (KSPLINE + NIN)   // 6144
#define SPLITS  16
#define BK      64
#define KCHUNK  (KDIM / SPLITS)   // 384

typedef short bf16x8 __attribute__((ext_vector_type(8)));
typedef float f32x4  __attribute__((ext_vector_type(4)));
typedef unsigned short ushort8 __attribute__((ext_vector_type(8)));

__device__ __forceinline__ unsigned short f2bf(float f) {
  unsigned u = __float_as_uint(f);
  u += 0x7fff + ((u >> 16) & 1);   // RNE to bf16
  return (unsigned short)(u >> 16);
}

// K1 fused prep:
//  blocks [0,2048):    basis+silu -> A [1024][6144] bf16, LDS-staged 16B stores
//  blocks [2048,3584): Bt[o][kk] = c[i][o][k]*w[i][o] (or w for the silu cols),
//                      8 outputs/thread packed into one 16B store.
__global__ __launch_bounds__(256) void k_prep(const float* __restrict__ x,
                                              const float* __restrict__ c,
                                              const float* __restrict__ w,
                                              unsigned short* __restrict__ A,
                                              unsigned short* __restrict__ Bt) {
  int blk = blockIdx.x;
  int tid = threadIdx.x;
  if (blk < 2048) {
    __shared__ unsigned short sb[256 * NB + 256];  // 6 KB: basis rows + silu
    int b  = blk >> 1;
    int i0 = (blk & 1) * 256;
    int i  = i0 + tid;
    float xv = x[b * NIN + i];
    float B[14];
#pragma unroll
    for (int j = 0; j < 14; ++j) {
      float t0 = -5.25f + 0.75f * (float)j;
      float t1 = t0 + 0.75f;
      B[j] = (xv >= t0 && xv < t1) ? 1.0f : 0.0f;
    }
#pragma unroll
    for (int d = 1; d <= 3; ++d) {
      float inv = 1.0f / (0.75f * (float)d);
#pragma unroll
      for (int j = 0; j <= 13 - d; ++j) {
        float tj   = -5.25f + 0.75f * (float)j;
        float tjd1 = tj + 0.75f * (float)(d + 1);
        B[j] = (xv - tj) * inv * B[j] + (tjd1 - xv) * inv * B[j + 1];
      }
    }
#pragma unroll
    for (int j = 0; j < NB; ++j) sb[tid * NB + j] = f2bf(B[j]);
    float sig = 1.0f / (1.0f + __expf(-xv));
    sb[256 * NB + tid] = f2bf(xv * sig);
    __syncthreads();
    // cooperative 16B copy: 352 chunks of basis + 32 chunks of silu
    char* Ab = (char*)A;
    const f32x4* src = (const f32x4*)sb;
    size_t base = (size_t)b * KDIM * 2;
#pragma unroll
    for (int t = tid; t < 384; t += 256) {
      size_t dst;
      if (t < 352) dst = base + (size_t)i0 * NB * 2 + (size_t)t * 16;
      else         dst = base + (size_t)KSPLINE * 2 + (size_t)i0 * 2 + (size_t)(t - 352) * 16;
      *(f32x4*)(Ab + dst) = src[t];
    }
  } else {
    int bc  = blk - 2048;
    int o   = bc & 511;
    int seg = bc >> 9;                 // 0..2
    int kk0 = seg * 2048 + tid * 8;    // multiple of 8
    ushort8 r;
#pragma unroll
    for (int u = 0; u < 8; ++u) {
      int kk = kk0 + u;
      float v;
      if (kk < KSPLINE) {
        int i = kk / NB;
        int k = kk - i * NB;
        v = c[(size_t)i * KSPLINE + o * NB + k] * w[i * NOUT + o];
      } else {
        v = w[(kk - KSPLINE) * NOUT + o];
      }
      r[u] = f2bf(v);
    }
    *(ushort8*)&Bt[(size_t)o * KDIM + kk0] = r;
  }
}

// K2: split-K GEMM: part[split][b][o] = A[b, ks..] . Bt[o, ks..]
// 128x128 block tile, 4 waves 2x2, wave = 64x64 via 4x4 of 16x16x32 bf16 MFMA.
// XOR-swizzled LDS (conflict-free ds_read_b128). NO fences/atomics here —
// kernel dispatch boundary provides release/acquire for the partials.
__global__ __launch_bounds__(256) void k_gemm(const unsigned short* __restrict__ A,
                                              const unsigned short* __restrict__ Bt,
                                              float* __restrict__ out,
                                              int splits, int kchunk) {
  __shared__ unsigned short As[128 * BK];  // 16 KB
  __shared__ unsigned short Bs[128 * BK];  // 16 KB
  const int tid  = threadIdx.x;
  const int lane = tid & 63, wave = tid >> 6;
  const int wr = wave >> 1, wc = wave & 1;
  const int mbase = blockIdx.x * 128, nbase = blockIdx.y * 128;
  const int split = blockIdx.z;
  const int k0 = split * kchunk;

  f32x4 acc[4][4] = {};

  const int mrow = lane & 15;
  const int kq   = (lane >> 4) * 8;   // k-offset of this quarter-wave's frag
  const int swz  = mrow & 7;          // row-dependent XOR for LDS de-swizzle

  for (int kk = k0; kk < k0 + kchunk; kk += BK) {
    // stage A,Bt tiles: 128 rows x 64 bf16 = 128 B/row = 8 x 16B chunks.
    // LDS dest forced to base+lane*16 -> swizzle the GLOBAL column group.
#pragma unroll
    for (int it = 0; it < 4; ++it) {
      int ch  = it * 256 + tid;
      int row = ch >> 3;
      int cgl = ch & 7;
      int col = (cgl ^ (row & 7)) * 8;
      const unsigned short* ga = A  + (size_t)(mbase + row) * KDIM + kk + col;
      const unsigned short* gb = Bt + (size_t)(nbase + row) * KDIM + kk + col;
      unsigned short* la = As + (it * 256 + wave * 64) * 8;
      unsigned short* lb = Bs + (it * 256 + wave * 64) * 8;
      __builtin_amdgcn_global_load_lds((__attribute__((address_space(1))) const void*)ga,
                                       (__attribute__((address_space(3))) void*)la, 16, 0, 0);
      __builtin_amdgcn_global_load_lds((__attribute__((address_space(1))) const void*)gb,
                                       (__attribute__((address_space(3))) void*)lb, 16, 0, 0);
    }
    __syncthreads();

#pragma unroll
    for (int ks = 0; ks < BK; ks += 32) {
      bf16x8 af[4], bfr[4];
#pragma unroll
      for (int mt = 0; mt < 4; ++mt) {
        int row = wr * 64 + mt * 16 + mrow;
        int cg  = ((ks + kq) >> 3) ^ swz;
        af[mt] = *(const bf16x8*)&As[row * BK + cg * 8];
      }
#pragma unroll
      for (int nt = 0; nt < 4; ++nt) {
        int row = wc * 64 + nt * 16 + mrow;
        int cg  = ((ks + kq) >> 3) ^ swz;
        bfr[nt] = *(const bf16x8*)&Bs[row * BK + cg * 8];
      }
#pragma unroll
      for (int mt = 0; mt < 4; ++mt)
#pragma unroll
        for (int nt = 0; nt < 4; ++nt)
          acc[mt][nt] = __builtin_amdgcn_mfma_f32_16x16x32_bf16(af[mt], bfr[nt], acc[mt][nt], 0, 0, 0);
    }
    __syncthreads();
  }

  // epilogue: C/D layout col = lane&15, row = (lane>>4)*4 + reg
  const int rq = (lane >> 4) * 4;
  if (splits == 1) {
#pragma unroll
    for (int mt = 0; mt < 4; ++mt)
#pragma unroll
      for (int nt = 0; nt < 4; ++nt) {
        int colg = nbase + wc * 64 + nt * 16 + mrow;
#pragma unroll
        for (int r = 0; r < 4; ++r) {
          int rowg = mbase + wr * 64 + mt * 16 + rq + r;
          out[(size_t)rowg * NOUT + colg] = acc[mt][nt][r];
        }
      }
    return;
  }
  // partials: nontemporal (write-once, read-once by next kernel, cross-XCD)
#pragma unroll
  for (int mt = 0; mt < 4; ++mt)
#pragma unroll
    for (int nt = 0; nt < 4; ++nt) {
      int colg = nbase + wc * 64 + nt * 16 + mrow;
#pragma unroll
      for (int r = 0; r < 4; ++r) {
        int rowg = mbase + wr * 64 + mt * 16 + rq + r;
        __builtin_nontemporal_store(acc[mt][nt][r],
            &out[((size_t)split * BATCH + rowg) * NOUT + colg]);
      }
    }
}

// K3: out = sum over SPLITS partials (nontemporal reads)
__global__ __launch_bounds__(256) void k_reduce(const float* __restrict__ part,
                                                float* __restrict__ out) {
  int t = blockIdx.x * 256 + threadIdx.x;  // float4 index
  const f32x4* pv = (const f32x4*)part;
  f32x4 s = __builtin_nontemporal_load(&pv[t]);
#pragma unroll
  for (int sp = 1; sp < SPLITS; ++sp)
    s += __builtin_nontemporal_load(&pv[(size_t)sp * (BATCH * NOUT / 4) + t]);
  ((f32x4*)out)[t] = s;
}

extern "C" void kernel_launch(void* const* d_in, const int* in_sizes, int n_in,
                              void* d_out, int out_size, void* d_ws, size_t ws_size,
                              hipStream_t stream) {
  const float* x = (const float*)d_in[0];
  const float* c = (const float*)d_in[1];
  const float* w = (const float*)d_in[2];
  float* out = (float*)d_out;

  unsigned short* A  = (unsigned short*)d_ws;
  unsigned short* Bt = A + (size_t)BATCH * KDIM;
  size_t off_part = ((size_t)BATCH + NOUT) * KDIM * 2;
  float* part = (float*)((char*)d_ws + off_part);
  size_t need = off_part + (size_t)SPLITS * BATCH * NOUT * 4;

  k_prep<<<dim3(2048 + 512 * 3), 256, 0, stream>>>(x, c, w, A, Bt);
  if (ws_size >= need) {
    k_gemm<<<dim3(8, 4, SPLITS), 256, 0, stream>>>(A, Bt, part, SPLITS, KCHUNK);
    k_reduce<<<dim3((BATCH * NOUT / 4) / 256), 256, 0, stream>>>(part, out);
  } else {
    // fallback: single-pass GEMM straight to out (slower, correct)
    k_gemm<<<dim3(8, 4, 1), 256, 0, stream>>>(A, Bt, out, 1, KDIM);
  }
}

// Round 5
// 100.414 us; speedup vs baseline: 2.1158x; 1.1698x over previous
//
#include <hip/hip_runtime.h>

// Problem constants
#define BATCH 1024
#define NIN   512
#define NOUT  512
#define NB    11
#define KSPLINE (NIN * NB)        // 5632
#define KDIM    (KSPLINE + NIN)   // 6144
#define SPLITS  16
#define BK      64
#define KCHUNK  (KDIM / SPLITS)   // 384

typedef short bf16x8 __attribute__((ext_vector_type(8)));
typedef float f32x4  __attribute__((ext_vector_type(4)));
typedef unsigned short ushort8 __attribute__((ext_vector_type(8)));

__device__ __forceinline__ unsigned short f2bf(float f) {
  unsigned u = __float_as_uint(f);
  u += 0x7fff + ((u >> 16) & 1);   // RNE to bf16
  return (unsigned short)(u >> 16);
}

// K1 fused prep (all phases coalesced):
//  blocks [0,2048):      basis+silu -> A [1024][6144] bf16, LDS-staged 16B stores
//  blocks [2048,2176):   coef transpose: 16i x 128o tile. Coalesced c/w reads,
//                        LDS scatter to [o][i*11+k], contiguous 352B writes per o.
//  blocks [2176,2240):   w transpose for the silu columns of Bt (64x64 tiles).
__global__ __launch_bounds__(256) void k_prep(const float* __restrict__ x,
                                              const float* __restrict__ c,
                                              const float* __restrict__ w,
                                              unsigned short* __restrict__ A,
                                              unsigned short* __restrict__ Bt) {
  __shared__ char smem[53248];  // max of: basis 6KB | coefT 8KB+44KB | wT 8KB
  int blk = blockIdx.x;
  int tid = threadIdx.x;
  if (blk < 2048) {
    unsigned short* sb = (unsigned short*)smem;  // 256*NB + 256 ushorts
    int b  = blk >> 1;
    int i0 = (blk & 1) * 256;
    int i  = i0 + tid;
    float xv = x[b * NIN + i];
    float B[14];
#pragma unroll
    for (int j = 0; j < 14; ++j) {
      float t0 = -5.25f + 0.75f * (float)j;
      float t1 = t0 + 0.75f;
      B[j] = (xv >= t0 && xv < t1) ? 1.0f : 0.0f;
    }
#pragma unroll
    for (int d = 1; d <= 3; ++d) {
      float inv = 1.0f / (0.75f * (float)d);
#pragma unroll
      for (int j = 0; j <= 13 - d; ++j) {
        float tj   = -5.25f + 0.75f * (float)j;
        float tjd1 = tj + 0.75f * (float)(d + 1);
        B[j] = (xv - tj) * inv * B[j] + (tjd1 - xv) * inv * B[j + 1];
      }
    }
#pragma unroll
    for (int j = 0; j < NB; ++j) sb[tid * NB + j] = f2bf(B[j]);
    float sig = 1.0f / (1.0f + __expf(-xv));
    sb[256 * NB + tid] = f2bf(xv * sig);
    __syncthreads();
    // cooperative 16B copy: 352 chunks of basis + 32 chunks of silu
    char* Ab = (char*)A;
    const f32x4* src = (const f32x4*)sb;
    size_t base = (size_t)b * KDIM * 2;
    for (int t = tid; t < 384; t += 256) {
      size_t dst;
      if (t < 352) dst = base + (size_t)i0 * NB * 2 + (size_t)t * 16;
      else         dst = base + (size_t)KSPLINE * 2 + (size_t)i0 * 2 + (size_t)(t - 352) * 16;
      *(f32x4*)(Ab + dst) = src[t];
    }
  } else if (blk < 2176) {
    // ---- coef transpose tile: i0..i0+16 x o0..o0+128 ----
    float*          ws_ = (float*)smem;                    // 16*128 fp32 = 8 KB
    unsigned short* sbt = (unsigned short*)(smem + 8192);  // 128*176 ushort = 44 KB
    int bc = blk - 2048;
    int i0 = (bc & 31) * 16;
    int o0 = (bc >> 5) * 128;
    // stage w tile (coalesced): 16 rows x 128 o = 512 float4
    for (int ch = tid; ch < 512; ch += 256) {
      int i = ch >> 5, op = (ch & 31) * 4;
      *(f32x4*)&ws_[i * 128 + op] = *(const f32x4*)&w[(size_t)(i0 + i) * NOUT + o0 + op];
    }
    __syncthreads();
    // read c (coalesced 1408-float runs per i), scale by w, scatter to LDS [o'][i*11+k]
    for (int ch = tid; ch < 5632; ch += 256) {           // 16 i * 352 float4
      int i   = ch / 352;
      int off = (ch - i * 352) * 4;                      // [0,1408)
      f32x4 cv = *(const f32x4*)&c[(size_t)(i0 + i) * KSPLINE + (size_t)o0 * NB + off];
#pragma unroll
      for (int e = 0; e < 4; ++e) {
        int t  = off + e;
        int op = t / 11;
        int k  = t - op * 11;
        sbt[op * 176 + i * 11 + k] = f2bf(cv[e] * ws_[i * 128 + op]);
      }
    }
    __syncthreads();
    // write Bt: per o', 176 ushorts = 22 x 16B contiguous at Bt[o][i0*11]
    for (int ch = tid; ch < 2816; ch += 256) {           // 128 o' * 22 chunks
      int op = ch / 22;
      int q  = ch - op * 22;
      *(f32x4*)&Bt[(size_t)(o0 + op) * KDIM + i0 * NB + q * 8] =
          *(const f32x4*)&sbt[op * 176 + q * 8];
    }
  } else {
    // ---- silu columns: Bt[o][5632+i] = bf16(w[i][o]), 64x64 transpose tiles ----
    unsigned short* sw = (unsigned short*)smem;          // 64*64 ushort = 8 KB
    int bt = blk - 2176;
    int i0 = (bt & 7) * 64;
    int o0 = (bt >> 3) * 64;
    for (int ch = tid; ch < 1024; ch += 256) {           // 64 rows x 16 float4
      int r = ch >> 4, cc = (ch & 15) * 4;
      f32x4 v = *(const f32x4*)&w[(size_t)(i0 + r) * NOUT + o0 + cc];
#pragma unroll
      for (int e = 0; e < 4; ++e) sw[(cc + e) * 64 + r] = f2bf(v[e]);
    }
    __syncthreads();
    for (int ch = tid; ch < 512; ch += 256) {            // 64 o' x 8 chunks
      int op = ch >> 3, q = ch & 7;
      *(f32x4*)&Bt[(size_t)(o0 + op) * KDIM + KSPLINE + i0 + q * 8] =
          *(const f32x4*)&sw[op * 64 + q * 8];
    }
  }
}

// K2: split-K GEMM: part[split][b][o] = A[b, ks..] . Bt[o, ks..]
// 128x128 block tile, 4 waves 2x2, wave = 64x64 via 4x4 of 16x16x32 bf16 MFMA.
// XOR-swizzled LDS (conflict-free ds_read_b128). NO fences/atomics — the
// dispatch boundary provides release/acquire for the partials.
__global__ __launch_bounds__(256) void k_gemm(const unsigned short* __restrict__ A,
                                              const unsigned short* __restrict__ Bt,
                                              float* __restrict__ out,
                                              int splits, int kchunk) {
  __shared__ unsigned short As[128 * BK];  // 16 KB
  __shared__ unsigned short Bs[128 * BK];  // 16 KB
  const int tid  = threadIdx.x;
  const int lane = tid & 63, wave = tid >> 6;
  const int wr = wave >> 1, wc = wave & 1;
  const int mbase = blockIdx.x * 128, nbase = blockIdx.y * 128;
  const int split = blockIdx.z;
  const int k0 = split * kchunk;

  f32x4 acc[4][4] = {};

  const int mrow = lane & 15;
  const int kq   = (lane >> 4) * 8;   // k-offset of this quarter-wave's frag
  const int swz  = mrow & 7;          // row-dependent XOR for LDS de-swizzle

  for (int kk = k0; kk < k0 + kchunk; kk += BK) {
#pragma unroll
    for (int it = 0; it < 4; ++it) {
      int ch  = it * 256 + tid;
      int row = ch >> 3;
      int cgl = ch & 7;
      int col = (cgl ^ (row & 7)) * 8;
      const unsigned short* ga = A  + (size_t)(mbase + row) * KDIM + kk + col;
      const unsigned short* gb = Bt + (size_t)(nbase + row) * KDIM + kk + col;
      unsigned short* la = As + (it * 256 + wave * 64) * 8;
      unsigned short* lb = Bs + (it * 256 + wave * 64) * 8;
      __builtin_amdgcn_global_load_lds((__attribute__((address_space(1))) const void*)ga,
                                       (__attribute__((address_space(3))) void*)la, 16, 0, 0);
      __builtin_amdgcn_global_load_lds((__attribute__((address_space(1))) const void*)gb,
                                       (__attribute__((address_space(3))) void*)lb, 16, 0, 0);
    }
    __syncthreads();

#pragma unroll
    for (int ks = 0; ks < BK; ks += 32) {
      bf16x8 af[4], bfr[4];
#pragma unroll
      for (int mt = 0; mt < 4; ++mt) {
        int row = wr * 64 + mt * 16 + mrow;
        int cg  = ((ks + kq) >> 3) ^ swz;
        af[mt] = *(const bf16x8*)&As[row * BK + cg * 8];
      }
#pragma unroll
      for (int nt = 0; nt < 4; ++nt) {
        int row = wc * 64 + nt * 16 + mrow;
        int cg  = ((ks + kq) >> 3) ^ swz;
        bfr[nt] = *(const bf16x8*)&Bs[row * BK + cg * 8];
      }
#pragma unroll
      for (int mt = 0; mt < 4; ++mt)
#pragma unroll
        for (int nt = 0; nt < 4; ++nt)
          acc[mt][nt] = __builtin_amdgcn_mfma_f32_16x16x32_bf16(af[mt], bfr[nt], acc[mt][nt], 0, 0, 0);
    }
    __syncthreads();
  }

  // epilogue: C/D layout col = lane&15, row = (lane>>4)*4 + reg
  const int rq = (lane >> 4) * 4;
  size_t obase = (splits == 1) ? 0 : (size_t)split * BATCH * NOUT;
#pragma unroll
  for (int mt = 0; mt < 4; ++mt)
#pragma unroll
    for (int nt = 0; nt < 4; ++nt) {
      int colg = nbase + wc * 64 + nt * 16 + mrow;
#pragma unroll
      for (int r = 0; r < 4; ++r) {
        int rowg = mbase + wr * 64 + mt * 16 + rq + r;
        out[obase + (size_t)rowg * NOUT + colg] = acc[mt][nt][r];
      }
    }
}

// K3: out = sum over SPLITS partials
__global__ __launch_bounds__(256) void k_reduce(const float* __restrict__ part,
                                                float* __restrict__ out) {
  int t = blockIdx.x * 256 + threadIdx.x;  // float4 index
  const f32x4* pv = (const f32x4*)part;
  f32x4 s = pv[t];
#pragma unroll
  for (int sp = 1; sp < SPLITS; ++sp)
    s += pv[(size_t)sp * (BATCH * NOUT / 4) + t];
  ((f32x4*)out)[t] = s;
}

extern "C" void kernel_launch(void* const* d_in, const int* in_sizes, int n_in,
                              void* d_out, int out_size, void* d_ws, size_t ws_size,
                              hipStream_t stream) {
  const float* x = (const float*)d_in[0];
  const float* c = (const float*)d_in[1];
  const float* w = (const float*)d_in[2];
  float* out = (float*)d_out;

  unsigned short* A  = (unsigned short*)d_ws;
  unsigned short* Bt = A + (size_t)BATCH * KDIM;
  size_t off_part = ((size_t)BATCH + NOUT) * KDIM * 2;
  float* part = (float*)((char*)d_ws + off_part);
  size_t need = off_part + (size_t)SPLITS * BATCH * NOUT * 4;

  k_prep<<<dim3(2048 + 128 + 64), 256, 0, stream>>>(x, c, w, A, Bt);
  if (ws_size >= need) {
    k_gemm<<<dim3(8, 4, SPLITS), 256, 0, stream>>>(A, Bt, part, SPLITS, KCHUNK);
    k_reduce<<<dim3((BATCH * NOUT / 4) / 256), 256, 0, stream>>>(part, out);
  } else {
    // fallback: single-pass GEMM straight to out (slower, correct)
    k_gemm<<<dim3(8, 4, 1), 256, 0, stream>>>(A, Bt, out, 1, KDIM);
  }
}

// Round 6
// 97.198 us; speedup vs baseline: 2.1858x; 1.0331x over previous
//
#include <hip/hip_runtime.h>

// Problem constants
#define BATCH 1024
#define NIN   512
#define NOUT  512
#define NB    11
#define KSPLINE (NIN * NB)        // 5632
#define KDIM    (KSPLINE + NIN)   // 6144
#define SPLITS  16
#define BK      64
#define KCHUNK  (KDIM / SPLITS)   // 384

typedef short bf16x8 __attribute__((ext_vector_type(8)));
typedef float f32x4  __attribute__((ext_vector_type(4)));
typedef unsigned short ushort8 __attribute__((ext_vector_type(8)));

__device__ __forceinline__ unsigned short f2bf(float f) {
  unsigned u = __float_as_uint(f);
  u += 0x7fff + ((u >> 16) & 1);   // RNE to bf16
  return (unsigned short)(u >> 16);
}
__device__ __forceinline__ float bf2f(unsigned short h) {
  return __uint_as_float((unsigned)h << 16);
}

// K1 fused prep (all phases coalesced):
//  blocks [0,2048):      basis+silu -> A [1024][6144] bf16, LDS-staged 16B stores
//  blocks [2048,2176):   coef transpose: 16i x 128o tile. Coalesced c/w reads,
//                        LDS scatter to [o][i*11+k], contiguous 352B writes per o.
//  blocks [2176,2240):   w transpose for the silu columns of Bt (64x64 tiles).
__global__ __launch_bounds__(256) void k_prep(const float* __restrict__ x,
                                              const float* __restrict__ c,
                                              const float* __restrict__ w,
                                              unsigned short* __restrict__ A,
                                              unsigned short* __restrict__ Bt) {
  __shared__ char smem[53248];
  int blk = blockIdx.x;
  int tid = threadIdx.x;
  if (blk < 2048) {
    unsigned short* sb = (unsigned short*)smem;  // 256*NB + 256 ushorts
    int b  = blk >> 1;
    int i0 = (blk & 1) * 256;
    int i  = i0 + tid;
    float xv = x[b * NIN + i];
    float B[14];
#pragma unroll
    for (int j = 0; j < 14; ++j) {
      float t0 = -5.25f + 0.75f * (float)j;
      float t1 = t0 + 0.75f;
      B[j] = (xv >= t0 && xv < t1) ? 1.0f : 0.0f;
    }
#pragma unroll
    for (int d = 1; d <= 3; ++d) {
      float inv = 1.0f / (0.75f * (float)d);
#pragma unroll
      for (int j = 0; j <= 13 - d; ++j) {
        float tj   = -5.25f + 0.75f * (float)j;
        float tjd1 = tj + 0.75f * (float)(d + 1);
        B[j] = (xv - tj) * inv * B[j] + (tjd1 - xv) * inv * B[j + 1];
      }
    }
#pragma unroll
    for (int j = 0; j < NB; ++j) sb[tid * NB + j] = f2bf(B[j]);
    float sig = 1.0f / (1.0f + __expf(-xv));
    sb[256 * NB + tid] = f2bf(xv * sig);
    __syncthreads();
    char* Ab = (char*)A;
    const f32x4* src = (const f32x4*)sb;
    size_t base = (size_t)b * KDIM * 2;
    for (int t = tid; t < 384; t += 256) {
      size_t dst;
      if (t < 352) dst = base + (size_t)i0 * NB * 2 + (size_t)t * 16;
      else         dst = base + (size_t)KSPLINE * 2 + (size_t)i0 * 2 + (size_t)(t - 352) * 16;
      *(f32x4*)(Ab + dst) = src[t];
    }
  } else if (blk < 2176) {
    // ---- coef transpose tile: i0..i0+16 x o0..o0+128 ----
    float*          ws_ = (float*)smem;                    // 8 KB
    unsigned short* sbt = (unsigned short*)(smem + 8192);  // 44 KB
    int bc = blk - 2048;
    int i0 = (bc & 31) * 16;
    int o0 = (bc >> 5) * 128;
    for (int ch = tid; ch < 512; ch += 256) {
      int i = ch >> 5, op = (ch & 31) * 4;
      *(f32x4*)&ws_[i * 128 + op] = *(const f32x4*)&w[(size_t)(i0 + i) * NOUT + o0 + op];
    }
    __syncthreads();
    for (int ch = tid; ch < 5632; ch += 256) {           // 16 i * 352 float4
      int i   = ch / 352;
      int off = (ch - i * 352) * 4;
      f32x4 cv = *(const f32x4*)&c[(size_t)(i0 + i) * KSPLINE + (size_t)o0 * NB + off];
#pragma unroll
      for (int e = 0; e < 4; ++e) {
        int t  = off + e;
        int op = t / 11;
        int k  = t - op * 11;
        sbt[op * 176 + i * 11 + k] = f2bf(cv[e] * ws_[i * 128 + op]);
      }
    }
    __syncthreads();
    for (int ch = tid; ch < 2816; ch += 256) {           // 128 o' * 22 chunks
      int op = ch / 22;
      int q  = ch - op * 22;
      *(f32x4*)&Bt[(size_t)(o0 + op) * KDIM + i0 * NB + q * 8] =
          *(const f32x4*)&sbt[op * 176 + q * 8];
    }
  } else {
    // ---- silu columns: Bt[o][5632+i] = bf16(w[i][o]) ----
    unsigned short* sw = (unsigned short*)smem;          // 8 KB
    int bt = blk - 2176;
    int i0 = (bt & 7) * 64;
    int o0 = (bt >> 3) * 64;
    for (int ch = tid; ch < 1024; ch += 256) {
      int r = ch >> 4, cc = (ch & 15) * 4;
      f32x4 v = *(const f32x4*)&w[(size_t)(i0 + r) * NOUT + o0 + cc];
#pragma unroll
      for (int e = 0; e < 4; ++e) sw[(cc + e) * 64 + r] = f2bf(v[e]);
    }
    __syncthreads();
    for (int ch = tid; ch < 512; ch += 256) {
      int op = ch >> 3, q = ch & 7;
      *(f32x4*)&Bt[(size_t)(o0 + op) * KDIM + KSPLINE + i0 + q * 8] =
          *(const f32x4*)&sw[op * 64 + q * 8];
    }
  }
}

// K2: split-K GEMM: part_bf16[split][b][o] = A[b, ks..] . Bt[o, ks..]
// 128x128 block tile, 4 waves 2x2, wave = 64x64 via 4x4 of 16x16x32 bf16 MFMA.
// XOR-swizzled LDS (conflict-free ds_read_b128). Partials stored bf16 (halved
// round-trip traffic). No fences/atomics — dispatch boundary orders partials.
__global__ __launch_bounds__(256) void k_gemm(const unsigned short* __restrict__ A,
                                              const unsigned short* __restrict__ Bt,
                                              unsigned short* __restrict__ part,
                                              float* __restrict__ out,
                                              int splits, int kchunk) {
  __shared__ unsigned short As[128 * BK];  // 16 KB
  __shared__ unsigned short Bs[128 * BK];  // 16 KB
  const int tid  = threadIdx.x;
  const int lane = tid & 63, wave = tid >> 6;
  const int wr = wave >> 1, wc = wave & 1;
  const int mbase = blockIdx.x * 128, nbase = blockIdx.y * 128;
  const int split = blockIdx.z;
  const int k0 = split * kchunk;

  f32x4 acc[4][4] = {};

  const int mrow = lane & 15;
  const int kq   = (lane >> 4) * 8;
  const int swz  = mrow & 7;

  for (int kk = k0; kk < k0 + kchunk; kk += BK) {
#pragma unroll
    for (int it = 0; it < 4; ++it) {
      int ch  = it * 256 + tid;
      int row = ch >> 3;
      int cgl = ch & 7;
      int col = (cgl ^ (row & 7)) * 8;
      const unsigned short* ga = A  + (size_t)(mbase + row) * KDIM + kk + col;
      const unsigned short* gb = Bt + (size_t)(nbase + row) * KDIM + kk + col;
      unsigned short* la = As + (it * 256 + wave * 64) * 8;
      unsigned short* lb = Bs + (it * 256 + wave * 64) * 8;
      __builtin_amdgcn_global_load_lds((__attribute__((address_space(1))) const void*)ga,
                                       (__attribute__((address_space(3))) void*)la, 16, 0, 0);
      __builtin_amdgcn_global_load_lds((__attribute__((address_space(1))) const void*)gb,
                                       (__attribute__((address_space(3))) void*)lb, 16, 0, 0);
    }
    __syncthreads();

#pragma unroll
    for (int ks = 0; ks < BK; ks += 32) {
      bf16x8 af[4], bfr[4];
#pragma unroll
      for (int mt = 0; mt < 4; ++mt) {
        int row = wr * 64 + mt * 16 + mrow;
        int cg  = ((ks + kq) >> 3) ^ swz;
        af[mt] = *(const bf16x8*)&As[row * BK + cg * 8];
      }
#pragma unroll
      for (int nt = 0; nt < 4; ++nt) {
        int row = wc * 64 + nt * 16 + mrow;
        int cg  = ((ks + kq) >> 3) ^ swz;
        bfr[nt] = *(const bf16x8*)&Bs[row * BK + cg * 8];
      }
#pragma unroll
      for (int mt = 0; mt < 4; ++mt)
#pragma unroll
        for (int nt = 0; nt < 4; ++nt)
          acc[mt][nt] = __builtin_amdgcn_mfma_f32_16x16x32_bf16(af[mt], bfr[nt], acc[mt][nt], 0, 0, 0);
    }
    __syncthreads();
  }

  // epilogue: C/D layout col = lane&15, row = (lane>>4)*4 + reg
  const int rq = (lane >> 4) * 4;
  if (splits == 1) {
#pragma unroll
    for (int mt = 0; mt < 4; ++mt)
#pragma unroll
      for (int nt = 0; nt < 4; ++nt) {
        int colg = nbase + wc * 64 + nt * 16 + mrow;
#pragma unroll
        for (int r = 0; r < 4; ++r) {
          int rowg = mbase + wr * 64 + mt * 16 + rq + r;
          out[(size_t)rowg * NOUT + colg] = acc[mt][nt][r];
        }
      }
    return;
  }
#pragma unroll
  for (int mt = 0; mt < 4; ++mt)
#pragma unroll
    for (int nt = 0; nt < 4; ++nt) {
      int colg = nbase + wc * 64 + nt * 16 + mrow;
#pragma unroll
      for (int r = 0; r < 4; ++r) {
        int rowg = mbase + wr * 64 + mt * 16 + rq + r;
        part[((size_t)split * BATCH + rowg) * NOUT + colg] = f2bf(acc[mt][nt][r]);
      }
    }
}

// K3: out = sum over SPLITS bf16 partials. Each thread: one ushort8 slot per
// split (coalesced 16B loads), fp32 accumulate, two f32x4 stores.
__global__ __launch_bounds__(256) void k_reduce(const unsigned short* __restrict__ part,
                                                float* __restrict__ out) {
  int t = blockIdx.x * 256 + threadIdx.x;  // ushort8 index, 65536 total
  const ushort8* pv = (const ushort8*)part;
  float s[8] = {};
#pragma unroll
  for (int sp = 0; sp < SPLITS; ++sp) {
    ushort8 v = pv[(size_t)sp * (BATCH * NOUT / 8) + t];
#pragma unroll
    for (int e = 0; e < 8; ++e) s[e] += bf2f(v[e]);
  }
  f32x4 lo = { s[0], s[1], s[2], s[3] };
  f32x4 hi = { s[4], s[5], s[6], s[7] };
  ((f32x4*)out)[t * 2]     = lo;
  ((f32x4*)out)[t * 2 + 1] = hi;
}

extern "C" void kernel_launch(void* const* d_in, const int* in_sizes, int n_in,
                              void* d_out, int out_size, void* d_ws, size_t ws_size,
                              hipStream_t stream) {
  const float* x = (const float*)d_in[0];
  const float* c = (const float*)d_in[1];
  const float* w = (const float*)d_in[2];
  float* out = (float*)d_out;

  unsigned short* A  = (unsigned short*)d_ws;
  unsigned short* Bt = A + (size_t)BATCH * KDIM;
  size_t off_part = ((size_t)BATCH + NOUT) * KDIM * 2;
  unsigned short* part = (unsigned short*)((char*)d_ws + off_part);
  size_t need = off_part + (size_t)SPLITS * BATCH * NOUT * 2;

  k_prep<<<dim3(2048 + 128 + 64), 256, 0, stream>>>(x, c, w, A, Bt);
  if (ws_size >= need) {
    k_gemm<<<dim3(8, 4, SPLITS), 256, 0, stream>>>(A, Bt, part, out, SPLITS, KCHUNK);
    k_reduce<<<dim3((BATCH * NOUT / 8) / 256), 256, 0, stream>>>(part, out);
  } else {
    // fallback: single-pass GEMM straight to out (slower, correct)
    k_gemm<<<dim3(8, 4, 1), 256, 0, stream>>>(A, Bt, part, out, 1, KDIM);
  }
}

// Round 7
// 92.456 us; speedup vs baseline: 2.2979x; 1.0513x over previous
//
#include <hip/hip_runtime.h>

// Problem constants
#define BATCH 1024
#define NIN   512
#define NOUT  512
#define NB    11
// K-dim layout: i*12 + j ; j in [0,11) = basis k, j==11 = silu/w column
#define KDIM  (NIN * 12)          // 6144
#define SPLITS 16
#define IPS    (NIN / SPLITS)     // 32 i per split
#define LDW    104                // padded LDS row (96 + 8), conflict-free for b128

typedef short bf16x8 __attribute__((ext_vector_type(8)));
typedef float f32x4  __attribute__((ext_vector_type(4)));
typedef unsigned short ushort8 __attribute__((ext_vector_type(8)));

__device__ __forceinline__ unsigned short f2bf(float f) {
  unsigned u = __float_as_uint(f);
  u += 0x7fff + ((u >> 16) & 1);   // RNE to bf16
  return (unsigned short)(u >> 16);
}
__device__ __forceinline__ float bf2f(unsigned short h) {
  return __uint_as_float((unsigned)h << 16);
}

// K1 prep (coef only now): 256 blocks, 8i x 128o tiles.
// Bt[o][i*12+k] = bf16(c[i][o][k] * w[i][o]) for k<11 ; Bt[o][i*12+11] = bf16(w[i][o]).
// Coalesced c reads (1408-float runs / i), LDS transpose, contiguous 192B writes / o.
__global__ __launch_bounds__(256) void k_prep(const float* __restrict__ c,
                                              const float* __restrict__ w,
                                              unsigned short* __restrict__ Bt) {
  __shared__ float          ws_[8 * 128];     // 4 KB
  __shared__ unsigned short sbt[128 * 96];    // 24 KB, [o_local][i_local*12+j]
  int tid = threadIdx.x;
  int bc  = blockIdx.x;
  int i0  = (bc >> 2) * 8;          // 64 i-tiles
  int o0  = (bc & 3) * 128;         // 4 o-tiles
  // stage w tile (coalesced): 8 x 128
  {
    int r = tid >> 5, oq = (tid & 31) * 4;
    *(f32x4*)&ws_[r * 128 + oq] = *(const f32x4*)&w[(size_t)(i0 + r) * NOUT + o0 + oq];
  }
  __syncthreads();
  // c: 8 i x 1408 contiguous floats; scale by w; scatter to [o][i*12+k]
  for (int n = 0; n < 11; ++n) {
    int ch  = n * 256 + tid;                   // 2816 float4 chunks
    int il  = ch / 352;
    int off = (ch - il * 352) * 4;             // [0,1408)
    f32x4 cv = *(const f32x4*)&c[(size_t)(i0 + il) * (NIN * NB) + (size_t)o0 * NB + off];
#pragma unroll
    for (int e = 0; e < 4; ++e) {
      int t  = off + e;
      int op = t / 11;
      int k  = t - op * 11;
      sbt[op * 96 + il * 12 + k] = f2bf(cv[e] * ws_[il * 128 + op]);
    }
  }
  // silu column j=11: Bt[o][i*12+11] = w[i][o]
  {
    int il = tid >> 5, oq = (tid & 31) * 4;
#pragma unroll
    for (int e = 0; e < 4; ++e)
      sbt[(oq + e) * 96 + il * 12 + 11] = f2bf(ws_[il * 128 + oq + e]);
  }
  __syncthreads();
  // writeout: per o_local 96 ushorts = 12 x 16B contiguous
  for (int n = 0; n < 6; ++n) {
    int ch = n * 256 + tid;                    // 1536 chunks
    int op = ch / 12, q = ch - op * 12;
    *(ushort8*)&Bt[(size_t)(o0 + op) * KDIM + i0 * 12 + q * 8] =
        *(const ushort8*)&sbt[op * 96 + q * 8];
  }
}

// K2: fused basis-gen + split-K GEMM.
// 128x128 tile, 4 waves 2x2, 4x4 of 16x16x32 bf16 MFMA. BK=96 local k (8 i).
// A fragments computed in-kernel from x via local cubic B-spline (4 nonzero
// weights, closed form on uniform knots) straight into padded LDS.
// B staged regs->ds_write_b128 into same padded layout. bf16 partials.
__global__ __launch_bounds__(256) void k_fused(const float* __restrict__ x,
                                               const unsigned short* __restrict__ Bt,
                                               unsigned short* __restrict__ part,
                                               float* __restrict__ out,
                                               int splits, int ipersplit) {
  __shared__ unsigned short As[128 * LDW];   // 26.6 KB
  __shared__ unsigned short Bs[128 * LDW];   // 26.6 KB
  const int tid  = threadIdx.x;
  const int lane = tid & 63, wave = tid >> 6;
  const int wr = wave >> 1, wc = wave & 1;
  const int mbase = blockIdx.x * 128, nbase = blockIdx.y * 128;
  const int split = blockIdx.z;
  const int istart = split * ipersplit;

  f32x4 acc[4][4] = {};
  const int mrow = lane & 15;
  const int kq   = (lane >> 4) * 8;

  const int iters = ipersplit / 8;
  for (int it = 0; it < iters; ++it) {
    int ib = istart + it * 8;
    // ---- A: 128 b-rows x 8 i -> basis+silu into As[b][il*12+j] ----
    {
      int bl  = tid >> 1;
      int il0 = (tid & 1) * 4;
      f32x4 xv = *(const f32x4*)&x[(size_t)(mbase + bl) * NIN + ib + il0];
      unsigned short* arow = &As[bl * LDW];
#pragma unroll
      for (int q = 0; q < 4; ++q) {
        int col = (il0 + q) * 12;
        // zero the 12 slots (24 B, 8-aligned)
        *(unsigned long long*)&arow[col]     = 0ULL;
        *(unsigned long long*)&arow[col + 4] = 0ULL;
        *(unsigned long long*)&arow[col + 8] = 0ULL;
        float xq = xv[q];
        float um = (xq + 5.25f) * (1.0f / 0.75f);
        int   m  = (int)floorf(um);
        if (m >= 0 && m <= 13) {
          float u  = um - (float)m;
          float u2 = u * u, u3 = u2 * u;
          float omu = 1.0f - u;
          float w3 = u3 * (1.0f / 6.0f);                                   // B_m
          float w2 = (-3.0f*u3 + 3.0f*u2 + 3.0f*u + 1.0f) * (1.0f/6.0f);   // B_{m-1}
          float w1 = (3.0f*u3 - 6.0f*u2 + 4.0f) * (1.0f/6.0f);             // B_{m-2}
          float w0 = omu * omu * omu * (1.0f / 6.0f);                      // B_{m-3}
          int j0 = m - 3;
          if (j0 >= 0 && j0 <= 10)         arow[col + j0]     = f2bf(w0);
          if (j0 + 1 >= 0 && j0 + 1 <= 10) arow[col + j0 + 1] = f2bf(w1);
          if (j0 + 2 >= 0 && j0 + 2 <= 10) arow[col + j0 + 2] = f2bf(w2);
          if (m <= 10)                     arow[col + m]      = f2bf(w3);
        }
        float sig = 1.0f / (1.0f + __expf(-xq));
        arow[col + 11] = f2bf(xq * sig);
      }
    }
    // ---- B: stage Bt tile 128o x 96k via regs -> padded LDS ----
#pragma unroll
    for (int n = 0; n < 6; ++n) {
      int ch  = n * 256 + tid;               // 1536 16B chunks
      int row = ch / 12;
      int cg  = ch - row * 12;
      ushort8 vb = *(const ushort8*)&Bt[(size_t)(nbase + row) * KDIM + ib * 12 + cg * 8];
      *(ushort8*)&Bs[row * LDW + cg * 8] = vb;
    }
    __syncthreads();

#pragma unroll
    for (int ks = 0; ks < 96; ks += 32) {
      bf16x8 af[4], bfr[4];
#pragma unroll
      for (int mt = 0; mt < 4; ++mt)
        af[mt] = *(const bf16x8*)&As[(wr * 64 + mt * 16 + mrow) * LDW + ks + kq];
#pragma unroll
      for (int nt = 0; nt < 4; ++nt)
        bfr[nt] = *(const bf16x8*)&Bs[(wc * 64 + nt * 16 + mrow) * LDW + ks + kq];
#pragma unroll
      for (int mt = 0; mt < 4; ++mt)
#pragma unroll
        for (int nt = 0; nt < 4; ++nt)
          acc[mt][nt] = __builtin_amdgcn_mfma_f32_16x16x32_bf16(af[mt], bfr[nt], acc[mt][nt], 0, 0, 0);
    }
    __syncthreads();
  }

  // epilogue: C/D layout col = lane&15, row = (lane>>4)*4 + reg
  const int rq = (lane >> 4) * 4;
  if (splits == 1) {
#pragma unroll
    for (int mt = 0; mt < 4; ++mt)
#pragma unroll
      for (int nt = 0; nt < 4; ++nt) {
        int colg = nbase + wc * 64 + nt * 16 + mrow;
#pragma unroll
        for (int r = 0; r < 4; ++r) {
          int rowg = mbase + wr * 64 + mt * 16 + rq + r;
          out[(size_t)rowg * NOUT + colg] = acc[mt][nt][r];
        }
      }
    return;
  }
#pragma unroll
  for (int mt = 0; mt < 4; ++mt)
#pragma unroll
    for (int nt = 0; nt < 4; ++nt) {
      int colg = nbase + wc * 64 + nt * 16 + mrow;
#pragma unroll
      for (int r = 0; r < 4; ++r) {
        int rowg = mbase + wr * 64 + mt * 16 + rq + r;
        part[((size_t)split * BATCH + rowg) * NOUT + colg] = f2bf(acc[mt][nt][r]);
      }
    }
}

// K3: out = sum over SPLITS bf16 partials (coalesced ushort8 loads)
__global__ __launch_bounds__(256) void k_reduce(const unsigned short* __restrict__ part,
                                                float* __restrict__ out) {
  int t = blockIdx.x * 256 + threadIdx.x;  // ushort8 index, 65536 total
  const ushort8* pv = (const ushort8*)part;
  float s[8] = {};
#pragma unroll
  for (int sp = 0; sp < SPLITS; ++sp) {
    ushort8 v = pv[(size_t)sp * (BATCH * NOUT / 8) + t];
#pragma unroll
    for (int e = 0; e < 8; ++e) s[e] += bf2f(v[e]);
  }
  f32x4 lo = { s[0], s[1], s[2], s[3] };
  f32x4 hi = { s[4], s[5], s[6], s[7] };
  ((f32x4*)out)[t * 2]     = lo;
  ((f32x4*)out)[t * 2 + 1] = hi;
}

extern "C" void kernel_launch(void* const* d_in, const int* in_sizes, int n_in,
                              void* d_out, int out_size, void* d_ws, size_t ws_size,
                              hipStream_t stream) {
  const float* x = (const float*)d_in[0];
  const float* c = (const float*)d_in[1];
  const float* w = (const float*)d_in[2];
  float* out = (float*)d_out;

  unsigned short* Bt = (unsigned short*)d_ws;
  size_t off_part = (size_t)NOUT * KDIM * 2;                 // 6.3 MB
  unsigned short* part = (unsigned short*)((char*)d_ws + off_part);
  size_t need = off_part + (size_t)SPLITS * BATCH * NOUT * 2;

  k_prep<<<dim3(256), 256, 0, stream>>>(c, w, Bt);
  if (ws_size >= need) {
    k_fused<<<dim3(8, 4, SPLITS), 256, 0, stream>>>(x, Bt, part, out, SPLITS, IPS);
    k_reduce<<<dim3((BATCH * NOUT / 8) / 256), 256, 0, stream>>>(part, out);
  } else {
    // fallback: single-pass straight to out (needs only Bt in ws)
    k_fused<<<dim3(8, 4, 1), 256, 0, stream>>>(x, Bt, part, out, 1, NIN);
  }
}